// Round 3
// baseline (647.050 us; speedup 1.0000x reference)
//
#include <hip/hip_runtime.h>
#include <hip/hip_bf16.h>
#include <math.h>

typedef __bf16 bf16_t;
typedef __bf16 bf16x8 __attribute__((ext_vector_type(8)));
typedef float  f32x4  __attribute__((ext_vector_type(4)));

#define MFMA16(a,b,c) __builtin_amdgcn_mfma_f32_16x16x32_bf16((a),(b),(c),0,0,0)

namespace {
constexpr int D    = 64;
constexpr int DIN  = 192;
constexpr int NN   = 30000;
constexpr int NE   = 480000;

constexpr int NBLK   = 256;             // 1 block / CU (LDS-bound)
constexpr int NTHR   = 512;             // 8 waves / block
constexpr int NUNITS = NE / 32;         // 15000 wave-units of 32 edges
constexpr int NWAVES = NBLK * (NTHR / 64);   // 2048

// W0^T stored UNPADDED at stride 192 with XOR swizzle: elem idx ^= ((row&7)<<3)
// (byte ^= ((row&7)<<4)).  Carry-free since bits 3-5 of row*192 are 0; spreads
// the 16 m-lanes of each b128 read across all 32 banks (2-way = free).
constexpr int W0R    = 192;             // row length (= stride, no pad)
constexpr int W0T_SZ = 64 * W0R;        // 12288 elems
constexpr int SW1    = 72;              // W1^T global slab stride (never in LDS)
constexpr int W1T_SZ = 64 * SW1;        //  4608 elems
constexpr int HBS    = 32 * 64;         // per-wave hidden buffer, stride 64 + XOR

// LDS: 4x W0^T persistent + 8 wave-private hidden buffers
constexpr int LDS_SCR = 4 * W0T_SZ;                 // 49152 elems
constexpr int LDS_TOT = LDS_SCR + 8 * HBS;          // 65536 elems = 131072 B (128 KiB, proven)

constexpr size_t WS_AGG_BYTES = (size_t)NN * D * 4;                  // fp32 agg
constexpr size_t WS_WT_BYTES  = (size_t)(4 * W0T_SZ + 4 * W1T_SZ) * 2;
constexpr size_t WS_FLAG_OFF  = WS_AGG_BYTES + WS_WT_BYTES;
}

// ---- dtype-generic fragment loads (always produce bf16) ---------------------
__device__ __forceinline__ bf16x8 ldA(const bf16_t* p) {
  return *(const bf16x8*)p;             // all callsites 16B-aligned
}
__device__ __forceinline__ bf16x8 ldA(const float* p) {
  const float4* q4 = (const float4*)p;  // callsites 32B-aligned
  const float4 u = q4[0], v = q4[1];
  bf16x8 r;
  r[0] = (bf16_t)u.x; r[1] = (bf16_t)u.y; r[2] = (bf16_t)u.z; r[3] = (bf16_t)u.w;
  r[4] = (bf16_t)v.x; r[5] = (bf16_t)v.y; r[6] = (bf16_t)v.z; r[7] = (bf16_t)v.w;
  return r;
}

__device__ __forceinline__ float silu_f(float v) { return v / (1.f + __expf(-v)); }
__device__ __forceinline__ float sigm_f(float v) { return 1.f / (1.f + __expf(-v)); }

// wave-local LDS fence: order cross-lane ds_write -> ds_read phases without a
// block barrier.  sched_barrier(0) pins DS/MFMA movement (rule #18); the
// lgkmcnt(0) drains the LDS pipe.
__device__ __forceinline__ void wfence() {
  __builtin_amdgcn_sched_barrier(0);
  asm volatile("s_waitcnt lgkmcnt(0)" ::: "memory");
  __builtin_amdgcn_sched_barrier(0);
}

// layer0, BOTH branches merged: [32 edges x 192] @ [192 x 64] twice, sharing
// the A fragments.  B from persistent swizzled LDS W0^T slabs.
// ksw[kt] = (kt*32 + q*8) ^ ((m&7)<<3)  (precomputed, loop-invariant)
__device__ __forceinline__ void mlp_l0m(f32x4 accL[2][4], f32x4 accG[2][4],
    const bf16_t* __restrict__ w0L, const bf16_t* __restrict__ w0G,
    const bf16x8 fa[6][2], const int ksw[6], int m)
{
  const f32x4 z = {0.f, 0.f, 0.f, 0.f};
  #pragma unroll
  for (int h = 0; h < 2; ++h)
    #pragma unroll
    for (int nt = 0; nt < 4; ++nt) { accL[h][nt] = z; accG[h][nt] = z; }
  __builtin_amdgcn_s_setprio(1);
  #pragma unroll
  for (int kt = 0; kt < 6; ++kt) {
    const bf16_t* pL = w0L + m * W0R + ksw[kt];
    const bf16_t* pG = w0G + m * W0R + ksw[kt];
    #pragma unroll
    for (int nt = 0; nt < 4; ++nt) {
      const bf16x8 bL = *(const bf16x8*)(pL + nt * 16 * W0R);
      const bf16x8 bG = *(const bf16x8*)(pG + nt * 16 * W0R);
      accL[0][nt] = MFMA16(fa[kt][0], bL, accL[0][nt]);
      accL[1][nt] = MFMA16(fa[kt][1], bL, accL[1][nt]);
      accG[0][nt] = MFMA16(fa[kt][0], bG, accG[0][nt]);
      accG[1][nt] = MFMA16(fa[kt][1], bG, accG[1][nt]);
    }
  }
  __builtin_amdgcn_s_setprio(0);
}

// preload one W1 branch's B-fragments (tile-invariant, L2-hot) into registers
__device__ __forceinline__ void loadW1(bf16x8 wb[2][4],
                                       const bf16_t* __restrict__ w1, int m, int q) {
  #pragma unroll
  for (int kt = 0; kt < 2; ++kt)
    #pragma unroll
    for (int nt = 0; nt < 4; ++nt)
      wb[kt][nt] = ldA(w1 + (nt * 16 + m) * SW1 + kt * 32 + q * 8);
}

// layer1: [32 edges x 64] @ [64 x 64], A from wave-private swizzled LDS hidden,
// B from preloaded registers.
__device__ __forceinline__ void mlp_l1r(f32x4 acc[2][4],
    const bf16_t* __restrict__ hb, const bf16x8 wb[2][4], const int ksw[6], int m)
{
  const f32x4 z = {0.f, 0.f, 0.f, 0.f};
  #pragma unroll
  for (int h = 0; h < 2; ++h)
    #pragma unroll
    for (int nt = 0; nt < 4; ++nt) acc[h][nt] = z;
  __builtin_amdgcn_s_setprio(1);
  #pragma unroll
  for (int kt = 0; kt < 2; ++kt) {
    const bf16x8 a0 = *(const bf16x8*)(hb + m * 64 + ksw[kt]);
    const bf16x8 a1 = *(const bf16x8*)(hb + (m + 16) * 64 + ksw[kt]);
    #pragma unroll
    for (int nt = 0; nt < 4; ++nt) {
      acc[0][nt] = MFMA16(a0, wb[kt][nt], acc[0][nt]);
      acc[1][nt] = MFMA16(a1, wb[kt][nt], acc[1][nt]);
    }
  }
  __builtin_amdgcn_s_setprio(0);
}

// C-layout acc (+bias, silu) -> wave-private swizzled LDS hidden as bf16
template<typename TB>
__device__ __forceinline__ void hidden_silu(const f32x4 acc[2][4],
    const TB* __restrict__ bias, bf16_t* __restrict__ hb, int m, int q)
{
  #pragma unroll
  for (int nt = 0; nt < 4; ++nt) {
    const float bv = (float)bias[nt * 16 + m];
    #pragma unroll
    for (int h = 0; h < 2; ++h) {
      #pragma unroll
      for (int r = 0; r < 4; ++r) {
        const float v = acc[h][nt][r] + bv;
        const int row = h * 16 + q * 4 + r;
        const int col = (nt * 16 + m) ^ (((q * 4 + r) & 7) << 3);
        hb[row * 64 + col] = (bf16_t)silu_f(v);
      }
    }
  }
}

// ---- dtype detection --------------------------------------------------------
__global__ void detect_kernel(const void* w0, int* flag) {
  __shared__ int cnt;
  if (threadIdx.x == 0) cnt = 0;
  __syncthreads();
  const unsigned short* u = (const unsigned short*)w0;
  const unsigned short v = u[2 * threadIdx.x];
  const int e = (v >> 7) & 0xFF;
  atomicAdd(&cnt, (e >= 100 && e <= 140) ? 1 : 0);
  __syncthreads();
  if (threadIdx.x == 0) *flag = (cnt >= 128) ? 1 : 0;  // 1 = bf16, 0 = fp32
}

struct PrepArgs { const void* w[8]; bf16_t* o[8]; };

// transpose weights into ws as bf16.  W0^T slabs are PRE-SWIZZLED (idx ^=
// ((row&7)<<3)) so the linear LDS staging copy lands the swizzled layout
// (rule #21: swizzle source + read, keep the copy linear).  W1 slabs padded.
template<typename T>
__global__ void prep_kernel(const int* flag, int want, PrepArgs a) {
  if (*flag != want) return;
  const int b = blockIdx.x, t = threadIdx.x;
  const T* w = (const T*)a.w[b];
  bf16_t* o = a.o[b];
  if (b < 4) {
    for (int i = t; i < DIN * D; i += 256) {
      const int n = i & 63, k = i >> 6;                 // W0[k][n] -> W0^T[n][k]
      o[(n * W0R + k) ^ ((n & 7) << 3)] = (bf16_t)(float)w[i];
    }
  } else {
    for (int i = t; i < D * D; i += 256) o[(i & 63) * SW1 + (i >> 6)] = (bf16_t)(float)w[i];
  }
}

template<typename T>
__global__ __launch_bounds__(NTHR, 2) void fused_kernel(
    const int* __restrict__ flag, int want,
    const T* __restrict__ nf, const T* __restrict__ ef,
    const int* __restrict__ src, const int* __restrict__ dst,
    const T* __restrict__ eLb0, const T* __restrict__ eLb1,
    const T* __restrict__ eGb0, const T* __restrict__ eGb1,
    const T* __restrict__ nLb0, const T* __restrict__ nLb1,
    const T* __restrict__ nGb0, const T* __restrict__ nGb1,
    const bf16_t* __restrict__ wt, float* __restrict__ agg,
    T* __restrict__ out_e)
{
  if (*flag != want) return;
  __shared__ __align__(16) bf16_t sm[LDS_TOT];
  const int t = threadIdx.x;

  { // stage 4x W0^T ONCE (persistent for the whole kernel; already swizzled)
    int4* ls = (int4*)sm; const int4* gs = (const int4*)wt;
    for (int i = t; i < (LDS_SCR >> 3); i += NTHR) ls[i] = gs[i];
  }
  __syncthreads();          // the ONLY block-wide barrier

  const int lane = t & 63;
  const int w    = t >> 6;            // wave 0..7, fully independent
  const int m    = lane & 15;
  const int q    = lane >> 4;
  bf16_t* hb = sm + LDS_SCR + w * HBS;         // wave-private scratch

  int ksw[6];                                   // swizzled k-offsets (loop-invariant)
  #pragma unroll
  for (int kt = 0; kt < 6; ++kt) ksw[kt] = (kt * 32 + q * 8) ^ ((m & 7) << 3);

  const bf16_t* w0eL = sm;
  const bf16_t* w0eG = sm + W0T_SZ;
  const bf16_t* w0nL = sm + 2 * W0T_SZ;
  const bf16_t* w0nG = sm + 3 * W0T_SZ;
  const bf16_t* w1g  = wt + 4 * W0T_SZ;        // global W1^T slabs: eL,eG,nL,nG

  for (int u = blockIdx.x * (NTHR / 64) + w; u < NUNITS; u += NWAVES) {
    const int e0 = u * 32;
    const int eA = e0 + m, eB = eA + 16;
    const int sA = src[eA], sB = src[eB];
    const int dA = dst[eA], dB = dst[eB];

    wfence();   // prev iteration's l1 reads of hb vs this iteration's writes

    // gather ALL layer0 A-fragments once: [src || edge || dst]
    bf16x8 fa[6][2];
    #pragma unroll
    for (int kt = 0; kt < 2; ++kt) {
      const int ko = kt * 32 + q * 8;
      fa[kt][0]     = ldA(nf + (size_t)sA * D + ko);
      fa[kt][1]     = ldA(nf + (size_t)sB * D + ko);
      fa[2 + kt][0] = ldA(ef + (size_t)eA * D + ko);
      fa[2 + kt][1] = ldA(ef + (size_t)eB * D + ko);
      fa[4 + kt][0] = ldA(nf + (size_t)dA * D + ko);
      fa[4 + kt][1] = ldA(nf + (size_t)dB * D + ko);
    }

    // preload edge-MLP W1 fragments (latency hidden under layer0)
    bf16x8 w1L[2][4], w1G[2][4];
    loadW1(w1L, w1g + 0 * W1T_SZ, m, q);
    loadW1(w1G, w1g + 1 * W1T_SZ, m, q);

    f32x4 accL[2][4], accG[2][4], hl[2][4], gl[2][4];

    // ===== edge MLP =====
    mlp_l0m(accL, accG, w0eL, w0eG, fa, ksw, m);
    hidden_silu(accL, eLb0, hb, m, q);
    wfence();
    mlp_l1r(hl, hb, w1L, ksw, m);          // layers branch, layer1
    wfence();
    hidden_silu(accG, eGb0, hb, m, q);
    wfence();
    mlp_l1r(gl, hb, w1G, ksw, m);          // gates branch, layer1
    wfence();

    // preload node-MLP W1 fragments (hidden under epilogue + node layer0)
    loadW1(w1L, w1g + 2 * W1T_SZ, m, q);
    loadW1(w1G, w1g + 3 * W1T_SZ, m, q);

    // edge epilogue: e_new = ef + silu(h)*sigm(g); store + keep bf16 in hb
    #pragma unroll
    for (int nt = 0; nt < 4; ++nt) {
      const int n = nt * 16 + m;
      const float bL = (float)eLb1[n];
      const float bG = (float)eGb1[n];
      #pragma unroll
      for (int h = 0; h < 2; ++h) {
        #pragma unroll
        for (int r = 0; r < 4; ++r) {
          const int e = e0 + h * 16 + q * 4 + r;
          const float hv = silu_f(hl[h][nt][r] + bL);
          const float gv = sigm_f(gl[h][nt][r] + bG);
          const float val = (float)ef[(size_t)e * D + n] + hv * gv;
          out_e[(size_t)e * D + n] = (T)val;
          const int row = h * 16 + q * 4 + r;
          const int col = n ^ (((q * 4 + r) & 7) << 3);
          hb[row * 64 + col] = (bf16_t)val;
        }
      }
    }
    wfence();
    // re-read e_new as A-fragments (replaces the ef mid fragments)
    #pragma unroll
    for (int kt = 0; kt < 2; ++kt) {
      fa[2 + kt][0] = ldA(hb + m * 64 + ksw[kt]);
      fa[2 + kt][1] = ldA(hb + (m + 16) * 64 + ksw[kt]);
    }
    wfence();

    // ===== node MLP =====
    mlp_l0m(accL, accG, w0nL, w0nG, fa, ksw, m);
    hidden_silu(accL, nLb0, hb, m, q);
    wfence();
    mlp_l1r(hl, hb, w1L, ksw, m);
    wfence();
    hidden_silu(accG, nGb0, hb, m, q);
    wfence();
    mlp_l1r(gl, hb, w1G, ksw, m);

    // node epilogue: scatter-add messages
    int d8[2][4];
    #pragma unroll
    for (int h = 0; h < 2; ++h)
      #pragma unroll
      for (int r = 0; r < 4; ++r)
        d8[h][r] = dst[e0 + h * 16 + q * 4 + r];

    #pragma unroll
    for (int nt = 0; nt < 4; ++nt) {
      const int n = nt * 16 + m;
      const float bL = (float)nLb1[n];
      const float bG = (float)nGb1[n];
      #pragma unroll
      for (int h = 0; h < 2; ++h) {
        #pragma unroll
        for (int r = 0; r < 4; ++r) {
          const float hv = silu_f(hl[h][nt][r] + bL);
          const float gv = sigm_f(gl[h][nt][r] + bG);
          atomicAdd(&agg[(size_t)d8[h][r] * D + n], hv * gv);
        }
      }
    }
  }
}

// h_new = node_feat + agg @ node_out_W   (one wave per node)
template<typename T>
__global__ __launch_bounds__(256) void node_out_kernel(
    const int* __restrict__ flag, int want,
    const T* __restrict__ nf, const float* __restrict__ agg,
    const T* __restrict__ Wo, T* __restrict__ out_h)
{
  if (*flag != want) return;
  __shared__ float wsh[D * D];
  const int t = threadIdx.x;
  for (int i = t; i < D * D; i += 256) wsh[i] = (float)Wo[i];
  __syncthreads();
  const int node = blockIdx.x * 4 + (t >> 6);
  const int j = t & 63;
  const float* arow = agg + node * D;
  float acc = 0.f;
  #pragma unroll
  for (int k = 0; k < D; ++k) acc = fmaf(arow[k], wsh[k * D + j], acc);
  out_h[node * D + j] = (T)((float)nf[node * D + j] + acc);
}

template<typename T>
static void launch_all(void* const* d_in, void* d_out, void* d_ws,
                       const int* flag, int want, bf16_t* wt, float* agg,
                       hipStream_t stream) {
  const T* nf  = (const T*)d_in[0];
  const T* ef  = (const T*)d_in[1];
  const int* src = (const int*)d_in[2];
  const int* dst = (const int*)d_in[3];
  T* out_h = (T*)d_out;
  T* out_e = out_h + (size_t)NN * D;

  fused_kernel<T><<<NBLK, NTHR, 0, stream>>>(flag, want, nf, ef, src, dst,
      (const T*)d_in[5],  (const T*)d_in[7],   // eLb0, eLb1
      (const T*)d_in[9],  (const T*)d_in[11],  // eGb0, eGb1
      (const T*)d_in[13], (const T*)d_in[15],  // nLb0, nLb1
      (const T*)d_in[17], (const T*)d_in[19],  // nGb0, nGb1
      wt, agg, out_e);
  node_out_kernel<T><<<NN / 4, 256, 0, stream>>>(flag, want, nf, agg,
      (const T*)d_in[20], out_h);
}

extern "C" void kernel_launch(void* const* d_in, const int* in_sizes, int n_in,
                              void* d_out, int out_size, void* d_ws, size_t ws_size,
                              hipStream_t stream) {
  float*  agg  = (float*)d_ws;
  bf16_t* wt   = (bf16_t*)((char*)d_ws + WS_AGG_BYTES);
  int*    flag = (int*)((char*)d_ws + WS_FLAG_OFF);

  hipMemsetAsync(d_ws, 0, WS_AGG_BYTES, stream);       // zero agg

  detect_kernel<<<1, 256, 0, stream>>>(d_in[4], flag); // probe eLW0 dtype

  PrepArgs pa;
  pa.w[0] = d_in[4];  pa.w[1] = d_in[8];  pa.w[2] = d_in[12]; pa.w[3] = d_in[16]; // W0s: eL,eG,nL,nG
  pa.w[4] = d_in[6];  pa.w[5] = d_in[10]; pa.w[6] = d_in[14]; pa.w[7] = d_in[18]; // W1s
  for (int i = 0; i < 4; ++i) pa.o[i]     = wt + i * W0T_SZ;
  for (int j = 0; j < 4; ++j) pa.o[4 + j] = wt + 4 * W0T_SZ + j * W1T_SZ;
  prep_kernel<float> <<<8, 256, 0, stream>>>(flag, 0, pa);
  prep_kernel<bf16_t><<<8, 256, 0, stream>>>(flag, 1, pa);

  launch_all<float> (d_in, d_out, d_ws, flag, 0, wt, agg, stream);
  launch_all<bf16_t>(d_in, d_out, d_ws, flag, 1, wt, agg, stream);
}